// Round 9
// baseline (440.323 us; speedup 1.0000x reference)
//
#include <hip/hip_runtime.h>
#include <hip/hip_bf16.h>

typedef __hip_bfloat16 bf16;
typedef __attribute__((ext_vector_type(8))) short short8;
typedef __attribute__((ext_vector_type(4))) short s16x4;
typedef __attribute__((ext_vector_type(4))) float f32x4;

__device__ __forceinline__ bf16 f2b(float f) { return __float2bfloat16(f); }
__device__ __forceinline__ short bfbits(float f) {
  union { float f; unsigned u; } x; x.f = f;
  unsigned r = x.u + 0x7fff + ((x.u >> 16) & 1);  // RNE
  return (short)(r >> 16);
}
// tanh(x) = sign(x) * (1-t)/(1+t), t = e^{-2|x|}  — ~8 VALU ops, err ~1e-6
__device__ __forceinline__ float tanh_fast(float x) {
  float t = __expf(-2.f * fabsf(x));
  float r = (1.f - t) * __builtin_amdgcn_rcpf(1.f + t);
  return copysignf(r, x);
}

#define BM 128
#define BN 128
#define BK 32

#define GLOAD_LDS16(gp, lp) __builtin_amdgcn_global_load_lds( \
    (const __attribute__((address_space(1))) void*)(gp), \
    (__attribute__((address_space(3))) void*)(lp), 16, 0, 0)

// ---------------- prep: bf16 weight layouts (coalesced transpose) ----------
// W2bf[n][k]=W2[n][k]; W2Tbf[n][k]=W2[k][n]; Wf2bf[n][k]=Wf2[n][k];
// W1n[j][k]=W1[k][j]; Wffn[j][k]=Wff[j][k]
__global__ __launch_bounds__(256) void prep(
    const float* __restrict__ W2, const float* __restrict__ Wf2,
    const float* __restrict__ W1, const float* __restrict__ Wff,
    bf16* __restrict__ W2bf, bf16* __restrict__ W2Tbf,
    bf16* __restrict__ Wf2bf, bf16* __restrict__ W1n,
    bf16* __restrict__ Wffn)
{
  __shared__ float T[32][33];
  const int tid = threadIdx.x, bx = blockIdx.x;
  const int tx = bx & 31, ty = bx >> 5;
  const int r = tid >> 3, c4 = (tid & 7) * 4;
  const long ibase = (long)(ty * 32 + r) * 1024 + tx * 32 + c4;

  f32x4 v = *(const f32x4*)(W2 + ibase);
  f32x4 vf = *(const f32x4*)(Wf2 + ibase);
  s16x4 sv, sf;
  #pragma unroll
  for (int j = 0; j < 4; ++j) {
    sv[j] = bfbits(v[j]); sf[j] = bfbits(vf[j]);
    T[r][c4 + j] = v[j];
  }
  *(s16x4*)(W2bf + ibase) = sv;
  *(s16x4*)(Wf2bf + ibase) = sf;
  __syncthreads();
  const int oc = tid >> 3, or4 = (tid & 7) * 4;
  s16x4 st;
  #pragma unroll
  for (int j = 0; j < 4; ++j) st[j] = bfbits(T[or4 + j][oc]);
  *(s16x4*)(W2Tbf + (long)(tx * 32 + oc) * 1024 + ty * 32 + or4) = st;

  if (bx < 32) {  // W1n (16x1024, transpose of W1) + Wffn (straight)
    #pragma unroll
    for (int rep = 0; rep < 2; ++rep) {
      int i = bx * 512 + rep * 256 + tid;
      int rr = i >> 10, cc = i & 1023;
      W1n[i] = f2b(W1[cc * 16 + rr]);
      Wffn[i] = f2b(Wff[i]);
    }
  }
}

// ---------------- K1: h1 = tanh(z@W1^T+b1); f1 = [z,u]@Wf1^T+bf1 -----------
// u = tanh(z@Wp^T+bp) computed once per 32-row block in LDS.
__global__ __launch_bounds__(256) void k1(
    const float* __restrict__ z, const float* __restrict__ W1,
    const float* __restrict__ b1, const float* __restrict__ Wp,
    const float* __restrict__ bp, const float* __restrict__ Wf1,
    const float* __restrict__ bf1v,
    bf16* __restrict__ h1, bf16* __restrict__ f1out, long grow0)
{
  __shared__ float zs[32][16];
  __shared__ float us[32][4];
  const int tid = threadIdx.x;
  const long r0 = (long)blockIdx.x * 32;
  for (int i = tid; i < 512; i += 256) {
    int r = i >> 4, c = i & 15;
    zs[r][c] = z[(grow0 + r0 + r) * 16 + c];
  }
  __syncthreads();
  if (tid < 128) {
    int r = tid >> 2, a = tid & 3;
    float acc = bp[a];
    #pragma unroll
    for (int k = 0; k < 16; ++k) acc = fmaf(zs[r][k], Wp[a * 16 + k], acc);
    us[r][a] = tanh_fast(acc);
  }
  __syncthreads();
  #pragma unroll
  for (int jj = 0; jj < 4; ++jj) {
    const int c = tid + jj * 256;
    {  // h1
      float w[16];
      #pragma unroll
      for (int k = 0; k < 16; ++k) w[k] = W1[c * 16 + k];
      const float bc = b1[c];
      for (int r = 0; r < 32; ++r) {
        float a = bc;
        #pragma unroll
        for (int k = 0; k < 16; ++k) a = fmaf(zs[r][k], w[k], a);
        h1[(r0 + r) * 1024 + c] = f2b(tanh_fast(a));
      }
    }
    {  // f1
      float wf[20];
      #pragma unroll
      for (int k = 0; k < 20; ++k) wf[k] = Wf1[c * 20 + k];
      const float bfc = bf1v[c];
      for (int r = 0; r < 32; ++r) {
        float f = bfc;
        #pragma unroll
        for (int k = 0; k < 16; ++k) f = fmaf(zs[r][k], wf[k], f);
        #pragma unroll
        for (int a = 0; a < 4; ++a) f = fmaf(us[r][a], wf[16 + a], f);
        f1out[(r0 + r) * 1024 + c] = f2b(f);
      }
    }
  }
}

// ---------------- MFMA GEMM, static-unrolled 2-phase + fused epilogues -----
// C = A[CKx1024] * B (Bp[n][k] layout). LDS k-chunk swizzle (T2 both-sides).
// 1-D grid, y-fast + bijective XCD swizzle: 8 y-blocks sharing an A-panel
// run consecutively on one XCD -> A fetched once via L2.
// K-loop FULLY unrolled: buf index and k-offsets compile-time (rule #20) ->
// staging addresses = 4 hoisted bases + imm offsets, ~zero per-iter VALU.
// EPI 0 (gemm0): x=a2. h2=tanh(x+b2); s1=1-h2^2; O2=gb=s1*Wh[c];
//                f=O1[idx] (=f1, precomputed); O1=g1f=tanh(f)+f*s1 IN PLACE.
// EPI 1 (gemm1): g1b = x*(1-h1^2) -> Ot(LDS) -> project @W1n^T -> Pp partials
// EPI 2 (gemm2): f=x+bf2; g2f=tanh(f)+f*(1-h1^2) -> Ot -> @Wffn^T -> Pp
template<int EPI>
__global__ __launch_bounds__(256) void gemm_k(
    const bf16* __restrict__ A, const bf16* __restrict__ Bp,
    const float* __restrict__ bias, const float* __restrict__ Whv,
    const bf16* __restrict__ h1,
    bf16* O1, bf16* __restrict__ O2,   // O1 NOT restrict: in-place f1->g1f
    const bf16* __restrict__ Wn, float* __restrict__ Pp, int ckRows)
{
  constexpr int SMEM = (EPI == 0) ? 32768 : 34816;
  __shared__ __align__(16) char smem[SMEM];
  const int tid = threadIdx.x;
  const int lane = tid & 63, wid = tid >> 6;
  const int wr = wid >> 1, wc = wid & 1;
  const int fr = lane & 15, kg = lane >> 4;

  // bijective XCD swizzle (nwg = 8*nx, divisible by 8) then y-fast decompose
  const int q = (int)gridDim.x >> 3;
  const int wgid = ((int)blockIdx.x & 7) * q + ((int)blockIdx.x >> 3);
  const long row0 = (long)(wgid >> 3) * BM;
  const int col0 = (wgid & 7) * BN;

  const int sr0 = tid >> 2;                            // staging row in tile
  const int sk0 = ((tid & 3) ^ ((tid >> 3) & 3)) * 8;  // pre-swizzled k-chunk
  const int swr = (fr >> 1) & 3;                       // read-side XOR term

  const bf16* gA0 = A + (row0 + sr0) * 1024 + sk0;
  const bf16* gA1 = gA0 + 64 * 1024;
  const bf16* gB0 = Bp + ((long)col0 + sr0) * 1024 + sk0;
  const bf16* gB1 = gB0 + 64 * 1024;
  const int rdA = (wr * 64 + fr) * 32 + (kg ^ swr) * 8;  // + m*512 imm
  const int rdB = (wc * 64 + fr) * 32 + (kg ^ swr) * 8;  // + n*512 imm

  f32x4 acc[4][4] = {};

  {  // prologue: stage buf0 k0=0
    bf16* as = (bf16*)smem; bf16* bs = (bf16*)smem + 8192;
    GLOAD_LDS16(gA0, as + tid * 8);        GLOAD_LDS16(gA1, as + 2048 + tid * 8);
    GLOAD_LDS16(gB0, bs + tid * 8);        GLOAD_LDS16(gB1, bs + 2048 + tid * 8);
  }
  __syncthreads();

  #pragma unroll
  for (int kt = 0; kt < 32; ++kt) {
    const int cur = kt & 1;                 // compile-time under full unroll
    if (kt < 31) {
      const int k0 = (kt + 1) * 32;
      bf16* as = (bf16*)smem + (cur ^ 1) * 4096;
      bf16* bs = (bf16*)smem + 8192 + (cur ^ 1) * 4096;
      GLOAD_LDS16(gA0 + k0, as + tid * 8);
      GLOAD_LDS16(gA1 + k0, as + 2048 + tid * 8);
      GLOAD_LDS16(gB0 + k0, bs + tid * 8);
      GLOAD_LDS16(gB1 + k0, bs + 2048 + tid * 8);
    }
    const bf16* as = (const bf16*)smem + cur * 4096;
    const bf16* bs = (const bf16*)smem + 8192 + cur * 4096;
    short8 af[4], bfr[4];
    #pragma unroll
    for (int m = 0; m < 4; ++m)
      af[m] = *(const short8*)(as + rdA + m * 512);
    #pragma unroll
    for (int n = 0; n < 4; ++n)
      bfr[n] = *(const short8*)(bs + rdB + n * 512);
    #pragma unroll
    for (int m = 0; m < 4; ++m)
      #pragma unroll
      for (int n = 0; n < 4; ++n)
        acc[m][n] = __builtin_amdgcn_mfma_f32_16x16x32_bf16(af[m], bfr[n], acc[m][n], 0, 0, 0);
    __syncthreads();  // drains vmcnt+lgkm: prefetch landed, reads done
  }

  if (EPI == 0) {
    #pragma unroll
    for (int m = 0; m < 4; ++m) {
      const long gr0 = row0 + wr * 64 + m * 16 + kg * 4;
      #pragma unroll
      for (int n = 0; n < 4; ++n) {
        const int gc = col0 + wc * 64 + n * 16 + fr;
        const float b2c = bias[gc], whc = Whv[gc];
        f32x4 v = acc[m][n];
        #pragma unroll
        for (int j = 0; j < 4; ++j) {
          const long idx = (gr0 + j) * 1024 + gc;
          float h = tanh_fast(v[j] + b2c);
          float s1v = 1.f - h * h;
          float f = __bfloat162float(((const bf16*)O1)[idx]);  // f1 in place
          O2[idx] = f2b(s1v * whc);
          O1[idx] = f2b(tanh_fast(f) + f * s1v);
        }
      }
    }
  } else {
    bf16* Ot = (bf16*)smem;  // [128][136] bf16, reuses As/Bs post-loop
    #pragma unroll
    for (int m = 0; m < 4; ++m) {
      const int rl0 = wr * 64 + m * 16 + kg * 4;
      const long gr0 = row0 + rl0;
      #pragma unroll
      for (int n = 0; n < 4; ++n) {
        const int cl = wc * 64 + n * 16 + fr;
        const int gc = col0 + cl;
        f32x4 v = acc[m][n];
        #pragma unroll
        for (int j = 0; j < 4; ++j) {
          const long idx = (gr0 + j) * 1024 + gc;
          float x = v[j];
          if (EPI == 1) {
            float hh = __bfloat162float(h1[idx]);
            Ot[(rl0 + j) * 136 + cl] = f2b(x * (1.f - hh * hh));
          } else {
            float f = x + bias[gc];
            float hh = __bfloat162float(h1[idx]);
            Ot[(rl0 + j) * 136 + cl] = f2b(tanh_fast(f) + f * (1.f - hh * hh));
          }
        }
      }
    }
    __syncthreads();
    #pragma unroll
    for (int sub = 0; sub < 2; ++sub) {
      const int rl0 = wid * 32 + sub * 16;
      f32x4 pacc = (f32x4){0.f, 0.f, 0.f, 0.f};
      #pragma unroll
      for (int ks = 0; ks < 4; ++ks) {
        short8 afrag = *(const short8*)(Ot + (rl0 + fr) * 136 + ks * 32 + kg * 8);
        short8 bfrag = *(const short8*)(Wn + fr * 1024 + col0 + ks * 32 + kg * 8);
        pacc = __builtin_amdgcn_mfma_f32_16x16x32_bf16(afrag, bfrag, pacc, 0, 0, 0);
      }
      #pragma unroll
      for (int j = 0; j < 4; ++j)
        Pp[(((long)(wgid & 7)) * ckRows + row0 + rl0 + kg * 4 + j) * 16 + fr] = pacc[j];
    }
  }
}

// ---------------- k7: out = J*(sum_cb(Pp0+Pp1) + bff) ----------------------
__global__ __launch_bounds__(256) void k7(
    const float* __restrict__ Pp0, const float* __restrict__ Pp1,
    const float* __restrict__ bff, float* __restrict__ out,
    long grow0, int ckRows)
{
  int i = blockIdx.x * 256 + threadIdx.x;
  int r = i >> 4, j = i & 15, jp = (j + 8) & 15;
  float s = bff[jp];
  #pragma unroll
  for (int cb = 0; cb < 8; ++cb) {
    long o = ((long)cb * ckRows + r) * 16 + jp;
    s += Pp0[o] + Pp1[o];
  }
  out[(grow0 + r) * 16 + j] = (j < 8) ? s : -s;
}

// ---------------- host ----------------
extern "C" void kernel_launch(void* const* d_in, const int* in_sizes, int n_in,
                              void* d_out, int out_size, void* d_ws, size_t ws_size,
                              hipStream_t stream) {
  const float* z   = (const float*)d_in[1];
  const float* W1  = (const float*)d_in[2];
  const float* b1  = (const float*)d_in[3];
  const float* W2  = (const float*)d_in[4];
  const float* b2  = (const float*)d_in[5];
  const float* Wh  = (const float*)d_in[6];
  const float* Wf1 = (const float*)d_in[8];
  const float* bf1 = (const float*)d_in[9];
  const float* Wf2 = (const float*)d_in[10];
  const float* bf2 = (const float*)d_in[11];
  const float* Wff = (const float*)d_in[12];
  const float* bff = (const float*)d_in[13];
  const float* Wp  = (const float*)d_in[14];
  const float* bp  = (const float*)d_in[15];
  float* out = (float*)d_out;
  const int N = in_sizes[1] / 16;

  char* p = (char*)d_ws;
  auto alloc = [&](size_t bytes) {
    char* q = p; p += (bytes + 255) & ~(size_t)255; return q;
  };
  bf16* W2bf  = (bf16*)alloc(1024 * 1024 * 2);
  bf16* W2Tbf = (bf16*)alloc(1024 * 1024 * 2);
  bf16* Wf2bf = (bf16*)alloc(1024 * 1024 * 2);
  bf16* W1n   = (bf16*)alloc(16 * 1024 * 2);
  bf16* Wffn  = (bf16*)alloc(16 * 1024 * 2);
  size_t wbytes = (size_t)(p - (char*)d_ws);

  int CK = N;  // chunk rows (power of two, divides N)
  // per-row: 3 bf16 act buffers (3*2048 B) + 2 Pp f32 partial sets (2*512 B)
  while (CK > 128 && wbytes + (size_t)CK * 7168 > ws_size) CK >>= 1;
  bf16* actA = (bf16*)alloc((size_t)CK * 2048);          // h1
  bf16* actB = (bf16*)alloc((size_t)CK * 2048);          // gb
  bf16* actD = (bf16*)alloc((size_t)CK * 2048);          // f1 -> g1f (in place)
  float* Pp0 = (float*)alloc((size_t)CK * 8 * 16 * 4);   // gemm1 partials
  float* Pp1 = (float*)alloc((size_t)CK * 8 * 16 * 4);   // gemm2 partials

  prep<<<1024, 256, 0, stream>>>(W2, Wf2, W1, Wff, W2bf, W2Tbf, Wf2bf, W1n, Wffn);

  const int gblocks = (CK / 128) * 8;
  for (long r0 = 0; r0 < N; r0 += CK) {
    k1<<<CK / 32, 256, 0, stream>>>(z, W1, b1, Wp, bp, Wf1, bf1, actA, actD, r0);
    gemm_k<0><<<gblocks, 256, 0, stream>>>(
        actA, W2bf, b2, Wh, nullptr, actD, actB, nullptr, nullptr, CK);
    gemm_k<1><<<gblocks, 256, 0, stream>>>(
        actB, W2Tbf, nullptr, nullptr, actA, nullptr, nullptr, W1n, Pp0, CK);
    gemm_k<2><<<gblocks, 256, 0, stream>>>(
        actD, Wf2bf, bf2, nullptr, actA, nullptr, nullptr, Wffn, Pp1, CK);
    k7<<<CK / 16, 256, 0, stream>>>(Pp0, Pp1, bff, out, r0, CK);
  }
}

// Round 11
// 357.458 us; speedup vs baseline: 1.2318x; 1.2318x over previous
//
#include <hip/hip_runtime.h>
#include <hip/hip_bf16.h>

typedef __hip_bfloat16 bf16;
typedef __attribute__((ext_vector_type(8))) short short8;
typedef __attribute__((ext_vector_type(4))) short s16x4;
typedef __attribute__((ext_vector_type(4))) float f32x4;

__device__ __forceinline__ bf16 f2b(float f) { return __float2bfloat16(f); }
__device__ __forceinline__ short bfbits(float f) {
  union { float f; unsigned u; } x; x.f = f;
  unsigned r = x.u + 0x7fff + ((x.u >> 16) & 1);  // RNE
  return (short)(r >> 16);
}
// tanh(x) = sign(x) * (1-t)/(1+t), t = e^{-2|x|}  — ~8 VALU ops, err ~1e-6
__device__ __forceinline__ float tanh_fast(float x) {
  float t = __expf(-2.f * fabsf(x));
  float r = (1.f - t) * __builtin_amdgcn_rcpf(1.f + t);
  return copysignf(r, x);
}

#define GLOAD_LDS16(gp, lp) __builtin_amdgcn_global_load_lds( \
    (const __attribute__((address_space(1))) void*)(gp), \
    (__attribute__((address_space(3))) void*)(lp), 16, 0, 0)

// ---------------- prep: bf16 weight layouts (coalesced transpose) ----------
__global__ __launch_bounds__(256) void prep(
    const float* __restrict__ W2, const float* __restrict__ Wf2,
    const float* __restrict__ W1, const float* __restrict__ Wff,
    bf16* __restrict__ W2bf, bf16* __restrict__ W2Tbf,
    bf16* __restrict__ Wf2bf, bf16* __restrict__ W1n,
    bf16* __restrict__ Wffn)
{
  __shared__ float T[32][33];
  const int tid = threadIdx.x, bx = blockIdx.x;
  const int tx = bx & 31, ty = bx >> 5;
  const int r = tid >> 3, c4 = (tid & 7) * 4;
  const long ibase = (long)(ty * 32 + r) * 1024 + tx * 32 + c4;

  f32x4 v = *(const f32x4*)(W2 + ibase);
  f32x4 vf = *(const f32x4*)(Wf2 + ibase);
  s16x4 sv, sf;
  #pragma unroll
  for (int j = 0; j < 4; ++j) {
    sv[j] = bfbits(v[j]); sf[j] = bfbits(vf[j]);
    T[r][c4 + j] = v[j];
  }
  *(s16x4*)(W2bf + ibase) = sv;
  *(s16x4*)(Wf2bf + ibase) = sf;
  __syncthreads();
  const int oc = tid >> 3, or4 = (tid & 7) * 4;
  s16x4 st;
  #pragma unroll
  for (int j = 0; j < 4; ++j) st[j] = bfbits(T[or4 + j][oc]);
  *(s16x4*)(W2Tbf + (long)(tx * 32 + oc) * 1024 + ty * 32 + or4) = st;

  if (bx < 32) {  // W1n (16x1024, transpose of W1) + Wffn (straight)
    #pragma unroll
    for (int rep = 0; rep < 2; ++rep) {
      int i = bx * 512 + rep * 256 + tid;
      int rr = i >> 10, cc = i & 1023;
      W1n[i] = f2b(W1[cc * 16 + rr]);
      Wffn[i] = f2b(Wff[i]);
    }
  }
}

// ---------------- K1: h1 = tanh(z@W1^T+b1); f1 = [z,u]@Wf1^T+bf1 -----------
__global__ __launch_bounds__(256) void k1(
    const float* __restrict__ z, const float* __restrict__ W1,
    const float* __restrict__ b1, const float* __restrict__ Wp,
    const float* __restrict__ bp, const float* __restrict__ Wf1,
    const float* __restrict__ bf1v,
    bf16* __restrict__ h1, bf16* __restrict__ f1out, long grow0)
{
  __shared__ float zs[32][16];
  __shared__ float us[32][4];
  const int tid = threadIdx.x;
  const long r0 = (long)blockIdx.x * 32;
  for (int i = tid; i < 512; i += 256) {
    int r = i >> 4, c = i & 15;
    zs[r][c] = z[(grow0 + r0 + r) * 16 + c];
  }
  __syncthreads();
  if (tid < 128) {
    int r = tid >> 2, a = tid & 3;
    float acc = bp[a];
    #pragma unroll
    for (int k = 0; k < 16; ++k) acc = fmaf(zs[r][k], Wp[a * 16 + k], acc);
    us[r][a] = tanh_fast(acc);
  }
  __syncthreads();
  #pragma unroll
  for (int jj = 0; jj < 4; ++jj) {
    const int c = tid + jj * 256;
    {  // h1
      float w[16];
      #pragma unroll
      for (int k = 0; k < 16; ++k) w[k] = W1[c * 16 + k];
      const float bc = b1[c];
      for (int r = 0; r < 32; ++r) {
        float a = bc;
        #pragma unroll
        for (int k = 0; k < 16; ++k) a = fmaf(zs[r][k], w[k], a);
        h1[(r0 + r) * 1024 + c] = f2b(tanh_fast(a));
      }
    }
    {  // f1
      float wf[20];
      #pragma unroll
      for (int k = 0; k < 20; ++k) wf[k] = Wf1[c * 20 + k];
      const float bfc = bf1v[c];
      for (int r = 0; r < 32; ++r) {
        float f = bfc;
        #pragma unroll
        for (int k = 0; k < 16; ++k) f = fmaf(zs[r][k], wf[k], f);
        #pragma unroll
        for (int a = 0; a < 4; ++a) f = fmaf(us[r][a], wf[16 + a], f);
        f1out[(r0 + r) * 1024 + c] = f2b(f);
      }
    }
  }
}

// ---------------- MFMA GEMM 256x256, 8 waves, BK=32, dbuf 2-phase ----------
// C = A[CKx1024] * B (Bp[n][k] layout). k-chunk swizzle (T2 both-sides).
// 8 waves = 2 (rows) x 4 (cols); wave tile 128x64; acc[8][4] f32x4.
// LDS: As dbuf @ 0/16KB, Bs dbuf @ 32KB/48KB (64KB).
// EPI 0 (gemm0): x=a2. h2=tanh(x+b2); s1=1-h2^2; O2=gb=s1*Wh[c];
//                f=O1[idx] (=f1 precomputed); O1=g1f=tanh(f)+f*s1 IN PLACE.
// EPI 1/2: g-tile -> Ot[256][136] in TWO column-half phases (stride 136 only
//          fits 128 cols — R10 bug was cl<=255 at stride 136), project each
//          half @Wn^T (4 k-steps), accumulate pacc, then write Pp partials.
template<int EPI>
__global__ __launch_bounds__(512, 2) void gemm_k(
    const bf16* __restrict__ A, const bf16* __restrict__ Bp,
    const float* __restrict__ bias, const float* __restrict__ Whv,
    const bf16* __restrict__ h1,
    bf16* O1, bf16* __restrict__ O2,   // O1 NOT restrict: in-place f1->g1f
    const bf16* __restrict__ Wn, float* __restrict__ Pp, int ckRows)
{
  constexpr int SMEM = (EPI == 0) ? 65536 : 69632;
  __shared__ __align__(16) char smem[SMEM];
  const int tid = threadIdx.x;
  const int lane = tid & 63, wid = tid >> 6;
  const int wr = wid >> 2, wc = wid & 3;
  const int fr = lane & 15, kg = lane >> 4;
  const long row0 = (long)blockIdx.x * 256;
  const int col0 = blockIdx.y * 256;

  const int sr0 = tid >> 2;                            // staging row (0..127)
  const int sk0 = ((tid & 3) ^ ((tid >> 3) & 3)) * 8;  // pre-swizzled k-chunk
  const int swr = (fr >> 1) & 3;                       // read-side XOR term

  const bf16* gA0 = A + (row0 + sr0) * 1024 + sk0;
  const bf16* gB0 = Bp + ((long)col0 + sr0) * 1024 + sk0;
  const int rdA = (wr * 128 + fr) * 32 + (kg ^ swr) * 8;  // + m*512
  const int rdB = (wc * 64 + fr) * 32 + (kg ^ swr) * 8;   // + n*512

  f32x4 acc[8][4] = {};

  {  // prologue: stage buf0, k0=0
    bf16* as = (bf16*)smem;
    bf16* bs = (bf16*)smem + 16384;
    GLOAD_LDS16(gA0, as + tid * 8);
    GLOAD_LDS16(gA0 + 128 * 1024, as + 4096 + tid * 8);
    GLOAD_LDS16(gB0, bs + tid * 8);
    GLOAD_LDS16(gB0 + 128 * 1024, bs + 4096 + tid * 8);
  }
  __syncthreads();

  #pragma unroll 2
  for (int kt = 0; kt < 32; ++kt) {
    const int cur = kt & 1;                // static under unroll-2
    if (kt < 31) {                         // prefetch next K-tile
      const int k0 = (kt + 1) * 32;
      bf16* as = (bf16*)smem + (cur ^ 1) * 8192;
      bf16* bs = (bf16*)smem + 16384 + (cur ^ 1) * 8192;
      GLOAD_LDS16(gA0 + k0, as + tid * 8);
      GLOAD_LDS16(gA0 + 128 * 1024 + k0, as + 4096 + tid * 8);
      GLOAD_LDS16(gB0 + k0, bs + tid * 8);
      GLOAD_LDS16(gB0 + 128 * 1024 + k0, bs + 4096 + tid * 8);
    }
    const bf16* as = (const bf16*)smem + cur * 8192;
    const bf16* bs = (const bf16*)smem + 16384 + cur * 8192;
    short8 af[8], bfr[4];
    #pragma unroll
    for (int m = 0; m < 8; ++m)
      af[m] = *(const short8*)(as + rdA + m * 512);
    #pragma unroll
    for (int n = 0; n < 4; ++n)
      bfr[n] = *(const short8*)(bs + rdB + n * 512);
    #pragma unroll
    for (int m = 0; m < 8; ++m)
      #pragma unroll
      for (int n = 0; n < 4; ++n)
        acc[m][n] = __builtin_amdgcn_mfma_f32_16x16x32_bf16(af[m], bfr[n], acc[m][n], 0, 0, 0);
    __syncthreads();  // drains vmcnt+lgkm: prefetch landed, reads done
  }

  if (EPI == 0) {
    #pragma unroll
    for (int m = 0; m < 8; ++m) {
      const long gr0 = row0 + wr * 128 + m * 16 + kg * 4;
      #pragma unroll
      for (int n = 0; n < 4; ++n) {
        const int gc = col0 + wc * 64 + n * 16 + fr;
        const float b2c = bias[gc], whc = Whv[gc];
        f32x4 v = acc[m][n];
        #pragma unroll
        for (int j = 0; j < 4; ++j) {
          const long idx = (gr0 + j) * 1024 + gc;
          float h = tanh_fast(v[j] + b2c);
          float s1v = 1.f - h * h;
          float f = __bfloat162float(((const bf16*)O1)[idx]);  // f1 in place
          O2[idx] = f2b(s1v * whc);
          O1[idx] = f2b(tanh_fast(f) + f * s1v);
        }
      }
    }
  } else {
    bf16* Ot = (bf16*)smem;  // [256][136] bf16 — holds ONE column half
    f32x4 pacc[2] = {};
    #pragma unroll
    for (int ph = 0; ph < 2; ++ph) {
      if ((wc >> 1) == ph) {  // this wave's 64 cols live in half ph
        #pragma unroll
        for (int m = 0; m < 8; ++m) {
          const int rl0 = wr * 128 + m * 16 + kg * 4;
          const long gr0 = row0 + rl0;
          #pragma unroll
          for (int n = 0; n < 4; ++n) {
            const int cl = (wc & 1) * 64 + n * 16 + fr;       // 0..127
            const int gc = col0 + ph * 128 + cl;
            f32x4 v = acc[m][n];
            #pragma unroll
            for (int j = 0; j < 4; ++j) {
              const long idx = (gr0 + j) * 1024 + gc;
              float x = v[j], g;
              if (EPI == 1) {
                float hh = __bfloat162float(h1[idx]);
                g = x * (1.f - hh * hh);
              } else {
                float f = x + bias[gc];
                float hh = __bfloat162float(h1[idx]);
                g = tanh_fast(f) + f * (1.f - hh * hh);
              }
              Ot[(rl0 + j) * 136 + cl] = f2b(g);
            }
          }
        }
      }
      __syncthreads();  // half-tile staged
      #pragma unroll
      for (int sub = 0; sub < 2; ++sub) {
        const int rl0 = wid * 32 + sub * 16;
        #pragma unroll
        for (int ks = 0; ks < 4; ++ks) {
          short8 afrag = *(const short8*)(Ot + (rl0 + fr) * 136 + ks * 32 + kg * 8);
          short8 bfrag = *(const short8*)(Wn + fr * 1024 + col0 + ph * 128 + ks * 32 + kg * 8);
          pacc[sub] = __builtin_amdgcn_mfma_f32_16x16x32_bf16(afrag, bfrag, pacc[sub], 0, 0, 0);
        }
      }
      if (ph == 0) __syncthreads();  // reads done before half 1 overwrites
    }
    #pragma unroll
    for (int sub = 0; sub < 2; ++sub) {
      const int rl0 = wid * 32 + sub * 16;
      #pragma unroll
      for (int j = 0; j < 4; ++j)
        Pp[(((long)blockIdx.y) * ckRows + row0 + rl0 + kg * 4 + j) * 16 + fr] = pacc[sub][j];
    }
  }
}

// ---------------- k7: out = J*(sum_cb(Pp0+Pp1) + bff) ----------------------
__global__ __launch_bounds__(256) void k7(
    const float* __restrict__ Pp0, const float* __restrict__ Pp1,
    const float* __restrict__ bff, float* __restrict__ out,
    long grow0, int ckRows)
{
  int i = blockIdx.x * 256 + threadIdx.x;
  int r = i >> 4, j = i & 15, jp = (j + 8) & 15;
  float s = bff[jp];
  #pragma unroll
  for (int cb = 0; cb < 4; ++cb) {
    long o = ((long)cb * ckRows + r) * 16 + jp;
    s += Pp0[o] + Pp1[o];
  }
  out[(grow0 + r) * 16 + j] = (j < 8) ? s : -s;
}

// ---------------- host ----------------
extern "C" void kernel_launch(void* const* d_in, const int* in_sizes, int n_in,
                              void* d_out, int out_size, void* d_ws, size_t ws_size,
                              hipStream_t stream) {
  const float* z   = (const float*)d_in[1];
  const float* W1  = (const float*)d_in[2];
  const float* b1  = (const float*)d_in[3];
  const float* W2  = (const float*)d_in[4];
  const float* b2  = (const float*)d_in[5];
  const float* Wh  = (const float*)d_in[6];
  const float* Wf1 = (const float*)d_in[8];
  const float* bf1 = (const float*)d_in[9];
  const float* Wf2 = (const float*)d_in[10];
  const float* bf2 = (const float*)d_in[11];
  const float* Wff = (const float*)d_in[12];
  const float* bff = (const float*)d_in[13];
  const float* Wp  = (const float*)d_in[14];
  const float* bp  = (const float*)d_in[15];
  float* out = (float*)d_out;
  const int N = in_sizes[1] / 16;

  char* p = (char*)d_ws;
  auto alloc = [&](size_t bytes) {
    char* q = p; p += (bytes + 255) & ~(size_t)255; return q;
  };
  bf16* W2bf  = (bf16*)alloc(1024 * 1024 * 2);
  bf16* W2Tbf = (bf16*)alloc(1024 * 1024 * 2);
  bf16* Wf2bf = (bf16*)alloc(1024 * 1024 * 2);
  bf16* W1n   = (bf16*)alloc(16 * 1024 * 2);
  bf16* Wffn  = (bf16*)alloc(16 * 1024 * 2);
  size_t wbytes = (size_t)(p - (char*)d_ws);

  int CK = N;  // chunk rows (power of two, divides N)
  // per-row: 3 bf16 act buffers (3*2048 B) + 2 Pp f32 partial sets (2*256 B)
  while (CK > 256 && wbytes + (size_t)CK * 6656 > ws_size) CK >>= 1;
  bf16* actA = (bf16*)alloc((size_t)CK * 2048);          // h1
  bf16* actB = (bf16*)alloc((size_t)CK * 2048);          // gb
  bf16* actD = (bf16*)alloc((size_t)CK * 2048);          // f1 -> g1f (in place)
  float* Pp0 = (float*)alloc((size_t)CK * 4 * 16 * 4);   // gemm1 partials
  float* Pp1 = (float*)alloc((size_t)CK * 4 * 16 * 4);   // gemm2 partials

  prep<<<1024, 256, 0, stream>>>(W2, Wf2, W1, Wff, W2bf, W2Tbf, Wf2bf, W1n, Wffn);

  const dim3 ggrid(CK / 256, 4);
  for (long r0 = 0; r0 < N; r0 += CK) {
    k1<<<CK / 32, 256, 0, stream>>>(z, W1, b1, Wp, bp, Wf1, bf1, actA, actD, r0);
    gemm_k<0><<<ggrid, 512, 0, stream>>>(
        actA, W2bf, b2, Wh, nullptr, actD, actB, nullptr, nullptr, CK);
    gemm_k<1><<<ggrid, 512, 0, stream>>>(
        actB, W2Tbf, nullptr, nullptr, actA, nullptr, nullptr, W1n, Pp0, CK);
    gemm_k<2><<<ggrid, 512, 0, stream>>>(
        actD, Wf2bf, bf2, nullptr, actA, nullptr, nullptr, Wffn, Pp1, CK);
    k7<<<CK / 16, 256, 0, stream>>>(Pp0, Pp1, bff, out, r0, CK);
  }
}

// Round 12
// 346.150 us; speedup vs baseline: 1.2721x; 1.0327x over previous
//
#include <hip/hip_runtime.h>
#include <hip/hip_bf16.h>

typedef __hip_bfloat16 bf16;
typedef __attribute__((ext_vector_type(8))) short short8;
typedef __attribute__((ext_vector_type(4))) short s16x4;
typedef __attribute__((ext_vector_type(4))) float f32x4;

__device__ __forceinline__ bf16 f2b(float f) { return __float2bfloat16(f); }
__device__ __forceinline__ short bfbits(float f) {
  union { float f; unsigned u; } x; x.f = f;
  unsigned r = x.u + 0x7fff + ((x.u >> 16) & 1);  // RNE
  return (short)(r >> 16);
}
// tanh(x) = sign(x) * (1-t)/(1+t), t = e^{-2|x|}  — ~8 VALU ops, err ~1e-6
__device__ __forceinline__ float tanh_fast(float x) {
  float t = __expf(-2.f * fabsf(x));
  float r = (1.f - t) * __builtin_amdgcn_rcpf(1.f + t);
  return copysignf(r, x);
}

#define GLOAD_LDS16(gp, lp) __builtin_amdgcn_global_load_lds( \
    (const __attribute__((address_space(1))) void*)(gp), \
    (__attribute__((address_space(3))) void*)(lp), 16, 0, 0)
#define SBAR() __builtin_amdgcn_s_barrier()
#define WAITV(n) do { asm volatile("s_waitcnt vmcnt(" #n ")" ::: "memory"); \
                      __builtin_amdgcn_sched_barrier(0); } while (0)

// ---------------- prep: bf16 weight layouts (coalesced transpose) ----------
__global__ __launch_bounds__(256) void prep(
    const float* __restrict__ W2, const float* __restrict__ Wf2,
    const float* __restrict__ W1, const float* __restrict__ Wff,
    bf16* __restrict__ W2bf, bf16* __restrict__ W2Tbf,
    bf16* __restrict__ Wf2bf, bf16* __restrict__ W1n,
    bf16* __restrict__ Wffn)
{
  __shared__ float T[32][33];
  const int tid = threadIdx.x, bx = blockIdx.x;
  const int tx = bx & 31, ty = bx >> 5;
  const int r = tid >> 3, c4 = (tid & 7) * 4;
  const long ibase = (long)(ty * 32 + r) * 1024 + tx * 32 + c4;

  f32x4 v = *(const f32x4*)(W2 + ibase);
  f32x4 vf = *(const f32x4*)(Wf2 + ibase);
  s16x4 sv, sf;
  #pragma unroll
  for (int j = 0; j < 4; ++j) {
    sv[j] = bfbits(v[j]); sf[j] = bfbits(vf[j]);
    T[r][c4 + j] = v[j];
  }
  *(s16x4*)(W2bf + ibase) = sv;
  *(s16x4*)(Wf2bf + ibase) = sf;
  __syncthreads();
  const int oc = tid >> 3, or4 = (tid & 7) * 4;
  s16x4 st;
  #pragma unroll
  for (int j = 0; j < 4; ++j) st[j] = bfbits(T[or4 + j][oc]);
  *(s16x4*)(W2Tbf + (long)(tx * 32 + oc) * 1024 + ty * 32 + or4) = st;

  if (bx < 32) {  // W1n (16x1024, transpose of W1) + Wffn (straight)
    #pragma unroll
    for (int rep = 0; rep < 2; ++rep) {
      int i = bx * 512 + rep * 256 + tid;
      int rr = i >> 10, cc = i & 1023;
      W1n[i] = f2b(W1[cc * 16 + rr]);
      Wffn[i] = f2b(Wff[i]);
    }
  }
}

// ---------------- K1: h1 = tanh(z@W1^T+b1); f1 = [z,u]@Wf1^T+bf1 -----------
__global__ __launch_bounds__(256) void k1(
    const float* __restrict__ z, const float* __restrict__ W1,
    const float* __restrict__ b1, const float* __restrict__ Wp,
    const float* __restrict__ bp, const float* __restrict__ Wf1,
    const float* __restrict__ bf1v,
    bf16* __restrict__ h1, bf16* __restrict__ f1out, long grow0)
{
  __shared__ float zs[32][16];
  __shared__ float us[32][4];
  const int tid = threadIdx.x;
  const long r0 = (long)blockIdx.x * 32;
  for (int i = tid; i < 512; i += 256) {
    int r = i >> 4, c = i & 15;
    zs[r][c] = z[(grow0 + r0 + r) * 16 + c];
  }
  __syncthreads();
  if (tid < 128) {
    int r = tid >> 2, a = tid & 3;
    float acc = bp[a];
    #pragma unroll
    for (int k = 0; k < 16; ++k) acc = fmaf(zs[r][k], Wp[a * 16 + k], acc);
    us[r][a] = tanh_fast(acc);
  }
  __syncthreads();
  #pragma unroll
  for (int jj = 0; jj < 4; ++jj) {
    const int c = tid + jj * 256;
    {  // h1
      float w[16];
      #pragma unroll
      for (int k = 0; k < 16; ++k) w[k] = W1[c * 16 + k];
      const float bc = b1[c];
      for (int r = 0; r < 32; ++r) {
        float a = bc;
        #pragma unroll
        for (int k = 0; k < 16; ++k) a = fmaf(zs[r][k], w[k], a);
        h1[(r0 + r) * 1024 + c] = f2b(tanh_fast(a));
      }
    }
    {  // f1
      float wf[20];
      #pragma unroll
      for (int k = 0; k < 20; ++k) wf[k] = Wf1[c * 20 + k];
      const float bfc = bf1v[c];
      for (int r = 0; r < 32; ++r) {
        float f = bfc;
        #pragma unroll
        for (int k = 0; k < 16; ++k) f = fmaf(zs[r][k], wf[k], f);
        #pragma unroll
        for (int a = 0; a < 4; ++a) f = fmaf(us[r][a], wf[16 + a], f);
        f1out[(r0 + r) * 1024 + c] = f2b(f);
      }
    }
  }
}

// ---------------- MFMA GEMM 256x256, 8 waves, BK=32, 4-deep counted vmcnt --
// C = A[CKx1024] * B (Bp[n][k] layout). k-chunk swizzle (T2 both-sides).
// 4 circular LDS buffers (32 KB each, 128 KB): iter kt stages tile kt+3 into
// buf[(kt+3)&3] (freed by barrier at end of kt-1), reads buf[kt&3] — all
// distinct mod 4, so DMA writes never touch a buffer being read. Counted
// s_waitcnt vmcnt(8) keeps 3 tiles (12 loads) in flight across RAW s_barrier
// (no full drain). Full unroll -> all buffer indices/wait counts static.
// EPI 0: x=a2. h2=tanh(x+b2); s1=1-h2^2; O2=gb=s1*Wh[c];
//        f=O1[idx] (=f1 precomputed); O1=g1f=tanh(f)+f*s1 IN PLACE.
// EPI 1/2: g-tile -> Ot[256][136] in two column-half phases, project @Wn^T,
//          write Pp partials (per col-block).
template<int EPI>
__global__ __launch_bounds__(512, 2) void gemm_k(
    const bf16* __restrict__ A, const bf16* __restrict__ Bp,
    const float* __restrict__ bias, const float* __restrict__ Whv,
    const bf16* __restrict__ h1,
    bf16* O1, bf16* __restrict__ O2,   // O1 NOT restrict: in-place f1->g1f
    const bf16* __restrict__ Wn, float* __restrict__ Pp, int ckRows)
{
  __shared__ __align__(16) char smem[131072];  // As[4] @0, Bs[4] @65536
  const int tid = threadIdx.x;
  const int lane = tid & 63, wid = tid >> 6;
  const int wr = wid >> 2, wc = wid & 3;
  const int fr = lane & 15, kg = lane >> 4;
  const long row0 = (long)blockIdx.x * 256;
  const int col0 = blockIdx.y * 256;

  const int sr0 = tid >> 2;                            // staging row (0..127)
  const int sk0 = ((tid & 3) ^ ((tid >> 3) & 3)) * 8;  // pre-swizzled k-chunk
  const int swr = (fr >> 1) & 3;                       // read-side XOR term

  const bf16* gA0 = A + (row0 + sr0) * 1024 + sk0;
  const bf16* gB0 = Bp + ((long)col0 + sr0) * 1024 + sk0;
  const int rdA = (wr * 128 + fr) * 32 + (kg ^ swr) * 8;  // + m*512
  const int rdB = (wc * 64 + fr) * 32 + (kg ^ swr) * 8;   // + n*512

  f32x4 acc[8][4] = {};

  auto stage = [&](int b, int k0) {
    bf16* as = (bf16*)smem + b * 8192;           // 16 KB per A buffer
    bf16* bs = (bf16*)smem + 32768 + b * 8192;   // Bs base at byte 65536
    GLOAD_LDS16(gA0 + k0, as + tid * 8);
    GLOAD_LDS16(gA0 + 128 * 1024 + k0, as + 4096 + tid * 8);
    GLOAD_LDS16(gB0 + k0, bs + tid * 8);
    GLOAD_LDS16(gB0 + 128 * 1024 + k0, bs + 4096 + tid * 8);
  };

  // prologue: tiles 0,1,2 -> bufs 0,1,2; wait tile 0 (8 = tiles 1,2 in flight)
  stage(0, 0); stage(1, 32); stage(2, 64);
  WAITV(8); SBAR();

  #pragma unroll
  for (int kt = 0; kt < 32; ++kt) {
    if (kt + 3 < 32) stage((kt + 3) & 3, (kt + 3) * 32);
    const bf16* as = (const bf16*)smem + (kt & 3) * 8192;
    const bf16* bs = (const bf16*)smem + 32768 + (kt & 3) * 8192;
    short8 af[8], bfr[4];
    #pragma unroll
    for (int m = 0; m < 8; ++m)
      af[m] = *(const short8*)(as + rdA + m * 512);
    #pragma unroll
    for (int n = 0; n < 4; ++n)
      bfr[n] = *(const short8*)(bs + rdB + n * 512);
    __builtin_amdgcn_s_setprio(1);
    #pragma unroll
    for (int m = 0; m < 8; ++m)
      #pragma unroll
      for (int n = 0; n < 4; ++n)
        acc[m][n] = __builtin_amdgcn_mfma_f32_16x16x32_bf16(af[m], bfr[n], acc[m][n], 0, 0, 0);
    __builtin_amdgcn_s_setprio(0);
    // retire next-needed tile only; keep 3 tiles (12 loads) in flight
    if (kt < 29)       WAITV(8);
    else if (kt == 29) WAITV(4);
    else if (kt == 30) WAITV(0);
    if (kt < 31) SBAR();
  }

  if (EPI == 0) {
    #pragma unroll
    for (int m = 0; m < 8; ++m) {
      const long gr0 = row0 + wr * 128 + m * 16 + kg * 4;
      #pragma unroll
      for (int n = 0; n < 4; ++n) {
        const int gc = col0 + wc * 64 + n * 16 + fr;
        const float b2c = bias[gc], whc = Whv[gc];
        f32x4 v = acc[m][n];
        #pragma unroll
        for (int j = 0; j < 4; ++j) {
          const long idx = (gr0 + j) * 1024 + gc;
          float h = tanh_fast(v[j] + b2c);
          float s1v = 1.f - h * h;
          float f = __bfloat162float(((const bf16*)O1)[idx]);  // f1 in place
          O2[idx] = f2b(s1v * whc);
          O1[idx] = f2b(tanh_fast(f) + f * s1v);
        }
      }
    }
  } else {
    __syncthreads();         // all waves done with K-loop LDS before Ot reuse
    bf16* Ot = (bf16*)smem;  // [256][136] bf16 — holds ONE column half
    f32x4 pacc[2] = {};
    #pragma unroll
    for (int ph = 0; ph < 2; ++ph) {
      if ((wc >> 1) == ph) {  // this wave's 64 cols live in half ph
        #pragma unroll
        for (int m = 0; m < 8; ++m) {
          const int rl0 = wr * 128 + m * 16 + kg * 4;
          const long gr0 = row0 + rl0;
          #pragma unroll
          for (int n = 0; n < 4; ++n) {
            const int cl = (wc & 1) * 64 + n * 16 + fr;       // 0..127
            const int gc = col0 + ph * 128 + cl;
            f32x4 v = acc[m][n];
            #pragma unroll
            for (int j = 0; j < 4; ++j) {
              const long idx = (gr0 + j) * 1024 + gc;
              float x = v[j], g;
              if (EPI == 1) {
                float hh = __bfloat162float(h1[idx]);
                g = x * (1.f - hh * hh);
              } else {
                float f = x + bias[gc];
                float hh = __bfloat162float(h1[idx]);
                g = tanh_fast(f) + f * (1.f - hh * hh);
              }
              Ot[(rl0 + j) * 136 + cl] = f2b(g);
            }
          }
        }
      }
      __syncthreads();  // half-tile staged
      #pragma unroll
      for (int sub = 0; sub < 2; ++sub) {
        const int rl0 = wid * 32 + sub * 16;
        #pragma unroll
        for (int ks = 0; ks < 4; ++ks) {
          short8 afrag = *(const short8*)(Ot + (rl0 + fr) * 136 + ks * 32 + kg * 8);
          short8 bfrag = *(const short8*)(Wn + fr * 1024 + col0 + ph * 128 + ks * 32 + kg * 8);
          pacc[sub] = __builtin_amdgcn_mfma_f32_16x16x32_bf16(afrag, bfrag, pacc[sub], 0, 0, 0);
        }
      }
      if (ph == 0) __syncthreads();  // reads done before half 1 overwrites
    }
    #pragma unroll
    for (int sub = 0; sub < 2; ++sub) {
      const int rl0 = wid * 32 + sub * 16;
      #pragma unroll
      for (int j = 0; j < 4; ++j)
        Pp[(((long)blockIdx.y) * ckRows + row0 + rl0 + kg * 4 + j) * 16 + fr] = pacc[sub][j];
    }
  }
}

// ---------------- k7: out = J*(sum_cb(Pp0+Pp1) + bff) ----------------------
__global__ __launch_bounds__(256) void k7(
    const float* __restrict__ Pp0, const float* __restrict__ Pp1,
    const float* __restrict__ bff, float* __restrict__ out,
    long grow0, int ckRows)
{
  int i = blockIdx.x * 256 + threadIdx.x;
  int r = i >> 4, j = i & 15, jp = (j + 8) & 15;
  float s = bff[jp];
  #pragma unroll
  for (int cb = 0; cb < 4; ++cb) {
    long o = ((long)cb * ckRows + r) * 16 + jp;
    s += Pp0[o] + Pp1[o];
  }
  out[(grow0 + r) * 16 + j] = (j < 8) ? s : -s;
}

// ---------------- host ----------------
extern "C" void kernel_launch(void* const* d_in, const int* in_sizes, int n_in,
                              void* d_out, int out_size, void* d_ws, size_t ws_size,
                              hipStream_t stream) {
  const float* z   = (const float*)d_in[1];
  const float* W1  = (const float*)d_in[2];
  const float* b1  = (const float*)d_in[3];
  const float* W2  = (const float*)d_in[4];
  const float* b2  = (const float*)d_in[5];
  const float* Wh  = (const float*)d_in[6];
  const float* Wf1 = (const float*)d_in[8];
  const float* bf1 = (const float*)d_in[9];
  const float* Wf2 = (const float*)d_in[10];
  const float* bf2 = (const float*)d_in[11];
  const float* Wff = (const float*)d_in[12];
  const float* bff = (const float*)d_in[13];
  const float* Wp  = (const float*)d_in[14];
  const float* bp  = (const float*)d_in[15];
  float* out = (float*)d_out;
  const int N = in_sizes[1] / 16;

  char* p = (char*)d_ws;
  auto alloc = [&](size_t bytes) {
    char* q = p; p += (bytes + 255) & ~(size_t)255; return q;
  };
  bf16* W2bf  = (bf16*)alloc(1024 * 1024 * 2);
  bf16* W2Tbf = (bf16*)alloc(1024 * 1024 * 2);
  bf16* Wf2bf = (bf16*)alloc(1024 * 1024 * 2);
  bf16* W1n   = (bf16*)alloc(16 * 1024 * 2);
  bf16* Wffn  = (bf16*)alloc(16 * 1024 * 2);
  size_t wbytes = (size_t)(p - (char*)d_ws);

  int CK = N;  // chunk rows (power of two, divides N)
  // per-row: 3 bf16 act buffers (3*2048 B) + 2 Pp f32 partial sets (2*256 B)
  while (CK > 256 && wbytes + (size_t)CK * 6656 > ws_size) CK >>= 1;
  bf16* actA = (bf16*)alloc((size_t)CK * 2048);          // h1
  bf16* actB = (bf16*)alloc((size_t)CK * 2048);          // gb
  bf16* actD = (bf16*)alloc((size_t)CK * 2048);          // f1 -> g1f (in place)
  float* Pp0 = (float*)alloc((size_t)CK * 4 * 16 * 4);   // gemm1 partials
  float* Pp1 = (float*)alloc((size_t)CK * 4 * 16 * 4);   // gemm2 partials

  prep<<<1024, 256, 0, stream>>>(W2, Wf2, W1, Wff, W2bf, W2Tbf, Wf2bf, W1n, Wffn);

  const dim3 ggrid(CK / 256, 4);
  for (long r0 = 0; r0 < N; r0 += CK) {
    k1<<<CK / 32, 256, 0, stream>>>(z, W1, b1, Wp, bp, Wf1, bf1, actA, actD, r0);
    gemm_k<0><<<ggrid, 512, 0, stream>>>(
        actA, W2bf, b2, Wh, nullptr, actD, actB, nullptr, nullptr, CK);
    gemm_k<1><<<ggrid, 512, 0, stream>>>(
        actB, W2Tbf, nullptr, nullptr, actA, nullptr, nullptr, W1n, Pp0, CK);
    gemm_k<2><<<ggrid, 512, 0, stream>>>(
        actD, Wf2bf, bf2, nullptr, actA, nullptr, nullptr, Wffn, Pp1, CK);
    k7<<<CK / 16, 256, 0, stream>>>(Pp0, Pp1, bff, out, r0, CK);
  }
}